// Round 8
// baseline (601.735 us; speedup 1.0000x reference)
//
#include <hip/hip_runtime.h>
#include <math.h>

#define NN 8192
#define CC 4096
#define BLK 256

// out = sum_c cnt_c * value_c * NUM_POS / N^2 ; NUM_POS=4, N=8192
#define SCALE (4.0f / (8192.0f * 8192.0f))

// K1: zero sums (64 MB) + counts (16 KB). Warm-shaped streaming stores.
__global__ __launch_bounds__(BLK) void zero_kernel(float4* __restrict__ sums4,
                                                   int4* __restrict__ counts4) {
    int gid = blockIdx.x * BLK + threadIdx.x;            // 2048*256 = 524288
    float4 z = make_float4(0.f, 0.f, 0.f, 0.f);
    #pragma unroll
    for (int i = 0; i < 8; ++i)                          // 8*524288 float4 = 64 MB
        sums4[(size_t)i * 524288 + gid] = z;
    if (gid < CC / 4) counts4[gid] = make_int4(0, 0, 0, 0);
}

// K2: per-class counts.
__global__ void build_counts(const int* __restrict__ label, int* __restrict__ counts) {
    int i = blockIdx.x * blockDim.x + threadIdx.x;
    if (i < NN) atomicAdd(&counts[label[i]], 1);
}

// K3: the 128 MB feat read, EXACT warm shape (R5: 6.4 TB/s): 2048 blocks x 256
// threads x 16 batched float4, arithmetic addresses. Row is wave-uniform per
// chunk -> label is a scalar load. Scatter via fire-and-forget fp32 atomics.
__global__ __launch_bounds__(BLK) void scatter_kernel(const float4* __restrict__ f4,
                                                      const int* __restrict__ label,
                                                      float* __restrict__ sums) {
    int idx = blockIdx.x * BLK + threadIdx.x;            // 524288
    int col4 = idx & 1023;                               // float4 column within row
    int row0 = idx >> 10;                                // 0..511, uniform per block

    float4 v[16];
    #pragma unroll
    for (int i = 0; i < 16; ++i)                         // all 16 loads in flight
        v[i] = f4[(size_t)i * 524288 + idx];

    #pragma unroll
    for (int i = 0; i < 16; ++i) {
        int lab = label[row0 + i * 512];                 // wave-uniform
        float* dst = sums + (size_t)lab * CC + col4 * 4;
        unsafeAtomicAdd(dst + 0, v[i].x);
        unsafeAtomicAdd(dst + 1, v[i].y);
        unsafeAtomicAdd(dst + 2, v[i].z);
        unsafeAtomicAdd(dst + 3, v[i].w);
    }
}

// K4: dense per-class logsumexp — R4's VERIFIED block-per-class reduction.
// One block per class; thread t (wave w, lane l) owns float4 slots
// w*256 + i*64 + l (i<4) -> all 1024 slots (full 16 KB row) covered.
__global__ __launch_bounds__(BLK) void lse_kernel(const float* __restrict__ sums,
                                                  const int* __restrict__ counts,
                                                  float* __restrict__ wval) {
    int c = blockIdx.x;
    int t = threadIdx.x;
    int lane = t & 63, w = t >> 6;

    int cnt = counts[c];
    if (cnt == 0) {
        if (t == 0) wval[c] = 0.0f;
        return;
    }

    const float4* row4 = (const float4*)(sums + (size_t)c * CC);
    int base_slot = w * 256 + lane;
    float4 v[4];
    #pragma unroll
    for (int i = 0; i < 4; ++i) v[i] = row4[base_slot + i * 64];

    float inv = 1.0f / (float)cnt;
    float vals[16];
    #pragma unroll
    for (int i = 0; i < 4; ++i) {
        vals[i * 4 + 0] = v[i].x * inv;
        vals[i * 4 + 1] = v[i].y * inv;
        vals[i * 4 + 2] = v[i].z * inv;
        vals[i * 4 + 3] = v[i].w * inv;
    }

    __shared__ float s_red[4];
    __shared__ float s_bcast;
    __shared__ float s_vc;

    // --- block max ---
    float wm = vals[0];
    #pragma unroll
    for (int j = 1; j < 16; ++j) wm = fmaxf(wm, vals[j]);
    #pragma unroll
    for (int off = 1; off < 64; off <<= 1) wm = fmaxf(wm, __shfl_xor(wm, off, 64));
    if (lane == 0) s_red[w] = wm;
    __syncthreads();
    if (t == 0) s_bcast = fmaxf(fmaxf(s_red[0], s_red[1]), fmaxf(s_red[2], s_red[3]));
    __syncthreads();
    float M = s_bcast;

    // --- block sum of exp(v - M); owner deposits v at column c ---
    // col c -> slot s_idx=c>>2 comp c&3; slot = w*256 + i*64 + l
    int s_idx = c >> 2, cj = c & 3;
    int ow = s_idx >> 8, orem = s_idx & 255;
    int oi = orem >> 6, ol = orem & 63;
    float se = 0.f;
    #pragma unroll
    for (int j = 0; j < 16; ++j) se += __expf(vals[j] - M);
    #pragma unroll
    for (int off = 1; off < 64; off <<= 1) se += __shfl_xor(se, off, 64);
    if (lane == 0) s_red[w] = se;
    if (t == ow * 64 + ol) s_vc = vals[oi * 4 + cj];
    __syncthreads();

    if (t == 0) {
        float S = s_red[0] + s_red[1] + s_red[2] + s_red[3];
        wval[c] = (float)cnt * (M + __logf(S) - s_vc);
    }
}

// K5: out = SCALE * sum of wval.
__global__ __launch_bounds__(BLK) void final_kernel(const float* __restrict__ wval,
                                                    float* __restrict__ out) {
    int t = threadIdx.x;
    const float4* v4 = (const float4*)wval;
    float s = 0.f;
    #pragma unroll
    for (int i = 0; i < CC / 4 / BLK; ++i) {
        float4 v = v4[i * BLK + t];
        s += v.x + v.y + v.z + v.w;
    }
    #pragma unroll
    for (int off = 1; off < 64; off <<= 1) s += __shfl_xor(s, off, 64);
    __shared__ float s_red[4];
    int lane = t & 63, w = t >> 6;
    if (lane == 0) s_red[w] = s;
    __syncthreads();
    if (t == 0) out[0] = (s_red[0] + s_red[1] + s_red[2] + s_red[3]) * SCALE;
}

extern "C" void kernel_launch(void* const* d_in, const int* in_sizes, int n_in,
                              void* d_out, int out_size, void* d_ws, size_t ws_size,
                              hipStream_t stream) {
    const float* feat = (const float*)d_in[0];
    const int* label = (const int*)d_in[1];
    float* out = (float*)d_out;

    float* sums = (float*)d_ws;                       // 4096*4096 fp32 = 64 MB
    int* counts = (int*)(sums + (size_t)CC * CC);     // 4096 ints
    float* wval = (float*)(counts + CC);              // 4096 floats

    zero_kernel<<<2048, BLK, 0, stream>>>((float4*)sums, (int4*)counts);
    build_counts<<<NN / BLK, BLK, 0, stream>>>(label, counts);
    scatter_kernel<<<2048, BLK, 0, stream>>>((const float4*)feat, label, sums);
    lse_kernel<<<CC, BLK, 0, stream>>>(sums, counts, wval);
    final_kernel<<<1, BLK, 0, stream>>>(wval, out);
}